// Round 6
// baseline (202.265 us; speedup 1.0000x reference)
//
#include <hip/hip_runtime.h>

// KNN k-th smallest distance, two-pass threshold-filter MFMA version, v4.
// dist = sqrt(2 - 2*dot(zn,rn)); sorted(dist)[k] == (k+1)-th LARGEST dot.
//  1) normalize_bf16: fused z+ref rows -> L2-normalized bf16
//  2) knn_pass<1>:  MFMA dots, epilogue = per-(chunk,wave,lane16) subset MAX
//     (subsets partition the refs -> 11th largest of the 1024 subset maxes is
//      a valid lower bound T on the true 11th-largest dot)
//  3) knn_threshold: per row, exact 11th-largest of 1024 subset maxes -> T
//  4) knn_pass<2>:  MFMA dots again, keep v >= T[row] via atomic append
//  5) knn_final: exact 11th-largest of survivors -> dist
//
// v4: NO LDS, NO barriers in the K-loop. Each of the 4 waves covers the same
// 64 q-rows (A-frags resident in 64 VGPRs) but a PRIVATE interleaved stream
// of 32-ref tiles; B fragments are loaded global->VGPR directly and the tile
// loop is an explicit 2-stage ping-pong pipeline (loads for tile t+1 issue
// before tile t's MFMAs). Round 5 showed the barriered K-loop serializes on
// the s_waitcnt vmcnt(0) drain (~75% idle); with no barrier the compiler is
// free to use fine-grained vmcnt. Round 4 lesson: __launch_bounds__ caps the
// UNIFIED VGPR+AGPR budget -> (256,2) = 256 regs vs ~210 needed (safe).

#define D_DIM 128
#define TQ 64          // queries per block; all 4 waves share them
#define NCH 16         // ref chunks (grid.y); 32x16 = 512 blocks = 2/CU
#define NSUB (NCH * 64) // subsets per row = chunk x wave x ln = 1024
#define CAP 256        // survivor capacity per row

typedef __bf16 bf16_t;
typedef bf16_t bf16x8 __attribute__((ext_vector_type(8)));
typedef float f32x4 __attribute__((ext_vector_type(4)));

__device__ __forceinline__ unsigned short f2bf(float f) {
    unsigned u = __float_as_uint(f);
    return (unsigned short)((u + 0x7fffu + ((u >> 16) & 1u)) >> 16);  // RNE
}

__global__ __launch_bounds__(256) void normalize_bf16(
    const float* __restrict__ z, const float* __restrict__ ref,
    unsigned short* __restrict__ zb, unsigned short* __restrict__ rb,
    int N, int M)
{
    const int w = threadIdx.x >> 6;
    const int l = threadIdx.x & 63;
    const int row = blockIdx.x * 4 + w;
    if (row >= N + M) return;
    const float* in; unsigned short* out; int r;
    if (row < N) { in = z;   out = zb; r = row; }
    else         { in = ref; out = rb; r = row - N; }
    const float2 v = ((const float2*)in)[(size_t)r * 64 + l];
    float ss = v.x * v.x + v.y * v.y;
    #pragma unroll
    for (int off = 32; off > 0; off >>= 1) ss += __shfl_xor(ss, off);
    const float inv = rsqrtf(ss);
    ushort2 o; o.x = f2bf(v.x * inv); o.y = f2bf(v.y * inv);
    ((ushort2*)out)[(size_t)r * 64 + l] = o;
}

// PASS==1: write subset maxes.  PASS==2: filter vs T, append survivors.
template <int PASS>
__global__ __launch_bounds__(256, 2) void knn_pass(
    const unsigned short* __restrict__ zb, const unsigned short* __restrict__ rb,
    float* __restrict__ maxes, const float* __restrict__ T,
    int* __restrict__ cnt, float* __restrict__ surv,
    int N, int M, int chunk)
{
    const int t = threadIdx.x;
    const int lane = t & 63;
    const int w = t >> 6;          // wave -> private ref stream (tiles % 4 == w)
    const int quad = lane >> 4;
    const int ln = lane & 15;
    const int qbase = blockIdx.x * TQ;
    const int c0 = blockIdx.y * chunk;
    const int c1 = min(c0 + chunk, M);

    // A fragments (loop-invariant, 64 VGPRs): lane (ln,quad) holds
    // A[m=ln][k=quad*8+j] for q-row rt*16+ln, k-step ks.
    bf16x8 afr[4][4];
    #pragma unroll
    for (int rt = 0; rt < 4; ++rt)
        #pragma unroll
        for (int ks = 0; ks < 4; ++ks)
            afr[rt][ks] = *(const bf16x8*)
                &zb[(size_t)(qbase + rt * 16 + ln) * D_DIM + ks * 32 + quad * 8];

    float mx[4][4];   // pass1: per-lane subset max, q-row rt*16+quad*4+r
    float tr[4][4];   // pass2: per-row thresholds
    #pragma unroll
    for (int rt = 0; rt < 4; ++rt)
        #pragma unroll
        for (int r = 0; r < 4; ++r) {
            if (PASS == 1) mx[rt][r] = -3.0f;
            else tr[rt][r] = T[qbase + rt * 16 + quad * 4 + r];
        }

    // B fragment gather for a 32-ref tile at g0: 8 x dwordx4 per lane.
    // (Tail overreads <= 31 rows past M land in the maxes region of d_ws.)
    auto load_b = [&](bf16x8 (&B)[2][4], int g0) {
        #pragma unroll
        for (int ct = 0; ct < 2; ++ct)
            #pragma unroll
            for (int ks = 0; ks < 4; ++ks)
                B[ct][ks] = *(const bf16x8*)
                    &rb[(size_t)(g0 + ct * 16 + ln) * D_DIM + ks * 32 + quad * 8];
    };

    auto compute = [&](const bf16x8 (&B)[2][4], int g0) {
        f32x4 acc[2][4];
        #pragma unroll
        for (int ct = 0; ct < 2; ++ct)
            #pragma unroll
            for (int rt = 0; rt < 4; ++rt) acc[ct][rt] = (f32x4){0.f,0.f,0.f,0.f};
        #pragma unroll
        for (int ks = 0; ks < 4; ++ks)
            #pragma unroll
            for (int ct = 0; ct < 2; ++ct)
                #pragma unroll
                for (int rt = 0; rt < 4; ++rt)
                    acc[ct][rt] = __builtin_amdgcn_mfma_f32_16x16x32_bf16(
                        afr[rt][ks], B[ct][ks], acc[ct][rt], 0, 0, 0);
        #pragma unroll
        for (int ct = 0; ct < 2; ++ct) {
            int g = g0 + ct * 16 + ln;
            if (g < c1) {
                if (PASS == 1) {
                    #pragma unroll
                    for (int rt = 0; rt < 4; ++rt)
                        #pragma unroll
                        for (int r = 0; r < 4; ++r)
                            mx[rt][r] = fmaxf(mx[rt][r], acc[ct][rt][r]);
                } else {
                    #pragma unroll
                    for (int rt = 0; rt < 4; ++rt)
                        #pragma unroll
                        for (int r = 0; r < 4; ++r) {
                            float v = acc[ct][rt][r];
                            if (v >= tr[rt][r]) {   // rare (~30 hits / 50000)
                                int row = qbase + rt * 16 + quad * 4 + r;
                                int slot = atomicAdd(&cnt[row], 1);
                                if (slot < CAP) surv[(size_t)row * CAP + slot] = v;
                            }
                        }
                }
            }
        }
    };

    // 2-stage ping-pong pipeline, unrolled x2 to avoid register moves.
    bf16x8 b0[2][4], b1[2][4];
    int g0 = c0 + w * 32;          // wave-private stream, stride 128
    load_b(b0, g0);
    while (true) {
        int g1 = g0 + 128;
        if (g1 < c1) load_b(b1, g1);
        compute(b0, g0);
        if (g1 >= c1) break;
        int g2 = g1 + 128;
        if (g2 < c1) load_b(b0, g2);
        compute(b1, g1);
        if (g2 >= c1) break;
        g0 = g2;
    }

    if (PASS == 1) {
        const int sub = (blockIdx.y * 4 + w) * 16 + ln;
        #pragma unroll
        for (int rt = 0; rt < 4; ++rt)
            #pragma unroll
            for (int r = 0; r < 4; ++r) {
                int row = qbase + rt * 16 + quad * 4 + r;
                maxes[(size_t)row * NSUB + sub] = mx[rt][r];
            }
    }
}

// 4 rows per block, one wave each. Exact (k+1)-th largest of NSUB maxes -> T.
__global__ __launch_bounds__(256) void knn_threshold(
    const float* __restrict__ maxes, const int* __restrict__ kp,
    float* __restrict__ T, int* __restrict__ cnt)
{
    const int row = blockIdx.x * 4 + (threadIdx.x >> 6);
    const int t = threadIdx.x & 63;
    float v[NSUB / 64];   // 16
    float lm = -3.0f;
    #pragma unroll
    for (int i = 0; i < NSUB / 64; ++i) {
        v[i] = maxes[(size_t)row * NSUB + t + 64 * i];
        lm = fmaxf(lm, v[i]);
    }
    const int kk = *kp;   // 10
    float cur = -3.0f;
    for (int it = 0; it <= kk; ++it) {
        float m = lm;
        #pragma unroll
        for (int off = 32; off > 0; off >>= 1) m = fmaxf(m, __shfl_xor(m, off));
        cur = m;
        unsigned long long b = __ballot(lm == m);
        if ((int)(__ffsll(b) - 1) == t) {
            bool rm = false;
            lm = -3.0f;
            #pragma unroll
            for (int i = 0; i < NSUB / 64; ++i) {
                if (!rm && v[i] == m) { v[i] = -3.0f; rm = true; }
                lm = fmaxf(lm, v[i]);
            }
        }
    }
    if (t == 0) { T[row] = cur; cnt[row] = 0; }
}

// 4 rows per block, one wave each. Exact (k+1)-th largest of survivors.
__global__ __launch_bounds__(256) void knn_final(
    const float* __restrict__ surv, const int* __restrict__ cnt,
    const int* __restrict__ kp, float* __restrict__ out)
{
    const int row = blockIdx.x * 4 + (threadIdx.x >> 6);
    const int t = threadIdx.x & 63;
    int c = cnt[row]; if (c > CAP) c = CAP;
    float v[CAP / 64];   // 4
    float lm = -3.0f;
    #pragma unroll
    for (int i = 0; i < CAP / 64; ++i) {
        int idx = t + 64 * i;
        v[i] = (idx < c) ? surv[(size_t)row * CAP + idx] : -3.0f;
        lm = fmaxf(lm, v[i]);
    }
    const int kk = *kp;
    float cur = -3.0f;
    for (int it = 0; it <= kk; ++it) {
        float m = lm;
        #pragma unroll
        for (int off = 32; off > 0; off >>= 1) m = fmaxf(m, __shfl_xor(m, off));
        cur = m;
        unsigned long long b = __ballot(lm == m);
        if ((int)(__ffsll(b) - 1) == t) {
            bool rm = false;
            lm = -3.0f;
            #pragma unroll
            for (int i = 0; i < CAP / 64; ++i) {
                if (!rm && v[i] == m) { v[i] = -3.0f; rm = true; }
                lm = fmaxf(lm, v[i]);
            }
        }
    }
    if (t == 0) out[row] = sqrtf(fmaxf(2.0f - 2.0f * cur, 1e-12f));
}

extern "C" void kernel_launch(void* const* d_in, const int* in_sizes, int n_in,
                              void* d_out, int out_size, void* d_ws, size_t ws_size,
                              hipStream_t stream) {
    const float* z   = (const float*)d_in[0];
    const float* ref = (const float*)d_in[1];
    const int*   kp  = (const int*)d_in[2];
    float* out = (float*)d_out;

    const int N = in_sizes[0] / D_DIM;   // 2048
    const int M = in_sizes[1] / D_DIM;   // 50000

    unsigned short* zbuf = (unsigned short*)d_ws;             // N*128 bf16
    unsigned short* rbuf = zbuf + (size_t)N * D_DIM;          // M*128 bf16
    float* maxes = (float*)(rbuf + (size_t)M * D_DIM);        // N*NSUB f32 (8MB)
    float* T     = maxes + (size_t)N * NSUB;                  // N f32
    int*   cnt   = (int*)(T + N);                             // N i32
    float* surv  = (float*)(cnt + N);                         // N*CAP f32 (2MB)

    normalize_bf16<<<(N + M + 3) / 4, 256, 0, stream>>>(z, ref, zbuf, rbuf, N, M);

    const int chunk = (M + NCH - 1) / NCH;    // 3125
    dim3 grid(N / TQ, NCH);                   // 32 x 16 = 512 blocks = 2/CU

    knn_pass<1><<<grid, 256, 0, stream>>>(zbuf, rbuf, maxes, nullptr,
                                          nullptr, nullptr, N, M, chunk);
    knn_threshold<<<N / 4, 256, 0, stream>>>(maxes, kp, T, cnt);
    knn_pass<2><<<grid, 256, 0, stream>>>(zbuf, rbuf, nullptr, T,
                                          cnt, surv, N, M, chunk);
    knn_final<<<N / 4, 256, 0, stream>>>(surv, cnt, kp, out);
}